// Round 5
// baseline (278.766 us; speedup 1.0000x reference)
//
#include <hip/hip_runtime.h>
#include <hip/hip_bf16.h>

// Problem constants
#define B_    2
#define T_    2048
#define C_    1024
#define H_    16
#define D_    64
#define SRCL_ 128

typedef short  short8 __attribute__((ext_vector_type(8)));   // 8 bf16 (4 VGPRs)
typedef float  f32x4  __attribute__((ext_vector_type(4)));
typedef unsigned short ushort4_t __attribute__((ext_vector_type(4)));

// Q pre-scale: 0.125 (1/sqrt(64)) * log2(e) so attn can use raw v_exp_f32 (2^x)
#define QSCALE 0.18033688011112042f

__device__ inline unsigned short f2bf(float f) {
    union { float f; unsigned u; } v; v.f = f;
    unsigned r = v.u + 0x7FFFu + ((v.u >> 16) & 1u);   // RNE
    return (unsigned short)(r >> 16);
}

#if __has_builtin(__builtin_amdgcn_exp2f)
#define EXP2F(x) __builtin_amdgcn_exp2f(x)
#else
#define EXP2F(x) exp2f(x)
#endif

// async global->LDS, 16B per lane; LDS dest = uniform base + lane*16
__device__ __forceinline__ void async_ld16(const void* g, void* l) {
    __builtin_amdgcn_global_load_lds(
        (const __attribute__((address_space(1))) unsigned int*)g,
        (__attribute__((address_space(3))) unsigned int*)l, 16, 0, 0);
}

// ---------------------------------------------------------------------------
// Kernel 1: fp32 -> bf16 conversion of x and the three weight matrices.
// ---------------------------------------------------------------------------
__global__ __launch_bounds__(256) void convert_all(
        const float* __restrict__ x,
        const float* __restrict__ wq,
        const float* __restrict__ wk,
        const float* __restrict__ wv,
        unsigned short* __restrict__ xb,
        unsigned short* __restrict__ wb)
{
    const int NX = (B_ * T_ * C_) / 4;
    const int NW = (C_ * C_) / 4;
    int i = blockIdx.x * 256 + threadIdx.x;
    const float4* src;
    ushort4_t* dst;
    if (i < NX)               { src = (const float4*)x;  dst = (ushort4_t*)xb;                }
    else if (i < NX + NW)     { src = (const float4*)wq; dst = (ushort4_t*)wb;                i -= NX; }
    else if (i < NX + 2*NW)   { src = (const float4*)wk; dst = (ushort4_t*)(wb + C_*C_);      i -= NX + NW; }
    else                      { src = (const float4*)wv; dst = (ushort4_t*)(wb + 2*C_*C_);    i -= NX + 2*NW; }
    float4 v = src[i];
    ushort4_t o;
    o.x = f2bf(v.x); o.y = f2bf(v.y); o.z = f2bf(v.z); o.w = f2bf(v.w);
    dst[i] = o;
}

// ---------------------------------------------------------------------------
// Kernel 2: fused QKV projection GEMM, global_load_lds staging.
// Epilogue: each wave's 64x64 output block staged in per-wave LDS (no extra
// barrier; same-wave DS in order) then written with LINEAR dwordx4 stores.
// Q is pre-scaled by 0.125*log2(e). V written in tiled layout [bh][jt][d][t].
// ---------------------------------------------------------------------------
__global__ __launch_bounds__(256) void gemm_qkv(
        const unsigned short* __restrict__ xb,   // [4096,1024]
        const unsigned short* __restrict__ wb,   // [3072,1024]
        const float* __restrict__ bq,
        const float* __restrict__ bk,
        const float* __restrict__ bv,
        unsigned short* __restrict__ qo,         // [B,H,T,D] (scaled)
        unsigned short* __restrict__ ko,         // [B,H,T,D]
        unsigned short* __restrict__ vto)        // tiled [bh][jt][64][64]
{
    __shared__ __align__(16) unsigned short As[128 * 32];
    __shared__ __align__(16) unsigned short Bs[128 * 32];
    __shared__ __align__(16) unsigned short Es[4][64 * 72];  // per-wave epilogue stage

    const int tid  = threadIdx.x;
    const int wave = tid >> 6;
    const int lane = tid & 63;
    const int lane15 = lane & 15;
    const int quad   = lane >> 4;
    const int wm = wave >> 1;
    const int wn = wave & 1;
    const int m0 = (blockIdx.x & 31) * 128;
    const int n0 = (blockIdx.x >> 5) * 128;

    f32x4 acc[4][4];
#pragma unroll
    for (int mi = 0; mi < 4; ++mi)
#pragma unroll
        for (int ni = 0; ni < 4; ++ni)
            acc[mi][ni] = (f32x4){0.f, 0.f, 0.f, 0.f};

    const int c0   = wave * 2;
    const int rowi0 = 16 * c0 + (lane >> 2);
    const int rowi1 = 16 * (c0 + 1) + (lane >> 2);
    const int col8 = (lane & 3) * 8;

    const unsigned short* xrow0 = &xb[(m0 + rowi0) * 1024 + col8];
    const unsigned short* xrow1 = &xb[(m0 + rowi1) * 1024 + col8];
    const unsigned short* wrow0 = &wb[(n0 + rowi0) * 1024 + col8];
    const unsigned short* wrow1 = &wb[(n0 + rowi1) * 1024 + col8];

    for (int k0 = 0; k0 < 1024; k0 += 32) {
        async_ld16(xrow0 + k0, &As[c0 * 512]);
        async_ld16(xrow1 + k0, &As[(c0 + 1) * 512]);
        async_ld16(wrow0 + k0, &Bs[c0 * 512]);
        async_ld16(wrow1 + k0, &Bs[(c0 + 1) * 512]);
        __syncthreads();

        short8 a[4], bf[4];
#pragma unroll
        for (int mi = 0; mi < 4; ++mi)
            a[mi] = *(const short8*)&As[(wm * 64 + mi * 16 + lane15) * 32 + quad * 8];
#pragma unroll
        for (int ni = 0; ni < 4; ++ni)
            bf[ni] = *(const short8*)&Bs[(wn * 64 + ni * 16 + lane15) * 32 + quad * 8];
#pragma unroll
        for (int mi = 0; mi < 4; ++mi)
#pragma unroll
            for (int ni = 0; ni < 4; ++ni)
                acc[mi][ni] = __builtin_amdgcn_mfma_f32_16x16x32_bf16(a[mi], bf[ni], acc[mi][ni], 0, 0, 0);
        __syncthreads();
    }

    // ---- epilogue ----
    // wave-uniform: 64 cols = exactly one head of one of {Q,K,V}; 64 rows = one
    // 64-aligned t-block inside one batch.
    const int colbase = n0 + wn * 64;
    const int which   = colbase >> 10;            // 0=q 1=k 2=v (uniform)
    const int jj0     = colbase & 1023;
    const int h       = jj0 >> 6;
    const int rowbase = m0 + wm * 64;
    const int bidx    = rowbase >> 11;
    const int t0      = rowbase & 2047;
    const size_t bh   = (size_t)bidx * H_ + h;
    const float* bias_p = (which == 0 ? bq : (which == 1 ? bk : bv)) + jj0;
    const float oscale  = (which == 0) ? QSCALE : 1.0f;

    unsigned short* stage = &Es[wave][0];
#pragma unroll
    for (int ni = 0; ni < 4; ++ni) {
        const float bias = bias_p[ni * 16 + lane15];
        const int d = ni * 16 + lane15;
#pragma unroll
        for (int mi = 0; mi < 4; ++mi) {
#pragma unroll
            for (int r = 0; r < 4; ++r) {
                const int tt = mi * 16 + quad * 4 + r;
                const unsigned short val = f2bf((acc[mi][ni][r] + bias) * oscale);
                if (which == 2) stage[d * 72 + tt] = val;   // V^T: [d][t]
                else            stage[tt * 72 + d] = val;   // Q/K: [t][d]
            }
        }
    }

    unsigned short* gdst;
    if (which == 0)      gdst = qo + (bh * T_ + t0) * D_;                 // contiguous 8KB
    else if (which == 1) gdst = ko + (bh * T_ + t0) * D_;                 // contiguous 8KB
    else                 gdst = vto + bh * (size_t)(T_ * D_) + (t0 >> 6) * 4096;

    // same-wave LDS: in-order, no barrier needed.
#pragma unroll
    for (int c = 0; c < 8; ++c) {
        const int idx = c * 64 + lane;            // 0..511 -> linear 16B chunks
        const int row = idx >> 3;
        const int cc8 = (idx & 7) * 8;
        *(short8*)&gdst[idx * 8] = *(const short8*)&stage[row * 72 + cc8];
    }
}

// ---------------------------------------------------------------------------
// Kernel 3: flash attention, no-online-max softmax (scores provably bounded:
// plain sum-exp == softmax), per-wave key slices, persistent balanced grid.
// 1024 blocks (all resident); block = (bh, 4 q-tiles of constant total work).
// ---------------------------------------------------------------------------
__global__ __launch_bounds__(256, 4) void attn(
        const unsigned short* __restrict__ qg,   // [B,H,T,D] pre-scaled
        const unsigned short* __restrict__ kg,   // [B,H,T,D]
        const unsigned short* __restrict__ vtg,  // tiled [bh][jt][64][64]
        float* __restrict__ out)                 // [B,T,C] fp32
{
    __shared__ __align__(16) unsigned short Ps[4][16 * 88];  // per-wave P (stride 88: conflict-free)
    __shared__ float Ob[3][64 * 17];                         // slice 1..3 O^T partials
    __shared__ float Lb[3][16];                              // slice 1..3 l partials

    const int tid  = threadIdx.x;
    const int s    = tid >> 6;                   // wave = key slice 0..3
    const int lane = tid & 63;
    const int lane15 = lane & 15;
    const int quad   = lane >> 4;

    const int bh = blockIdx.x & 31;              // same bh -> same XCD (L2 reuse)
    const int a  = blockIdx.x >> 5;              // 0..31
    const int b  = bh >> 4;
    const int h  = bh & 15;

    const unsigned short* Q  = qg  + (size_t)bh * T_ * D_;
    const unsigned short* K  = kg  + (size_t)bh * T_ * D_;
    const unsigned short* VT = vtg + (size_t)bh * T_ * D_;

    unsigned short* myPs = &Ps[s][0];

    // 4 q-tiles with constant total work (sum of rt = 254 for every block)
    const int rts[4] = {127 - a, a, 95 - a, 32 + a};

    for (int qq = 0; qq < 4; ++qq) {
        const int rt = rts[qq];
        const int i0 = rt * 16;

        const short8 qf0 = *(const short8*)&Q[(i0 + lane15) * 64 + quad * 8];
        const short8 qf1 = *(const short8*)&Q[(i0 + lane15) * 64 + 32 + quad * 8];

        f32x4 o_acc[4];
#pragma unroll
        for (int di = 0; di < 4; ++di) o_acc[di] = (f32x4){0.f, 0.f, 0.f, 0.f};
        float l_p = 0.f;

        const int jmaxE  = min(T_, i0 + 16 + SRCL_);
        const int ntiles = (jmaxE + 63) >> 6;
        const int myN    = (ntiles > s) ? ((ntiles - s + 3) >> 2) : 0;
        const int limit  = i0 + lane15 + SRCL_;

        if (myN > 0) {
            int jt = s;
            short8 kc0[4], kc1[4];
#pragma unroll
            for (int ni = 0; ni < 4; ++ni) {
                const unsigned short* Krow = &K[(jt * 64 + ni * 16 + lane15) * 64 + quad * 8];
                kc0[ni] = *(const short8*)Krow;
                kc1[ni] = *(const short8*)(Krow + 32);
            }

            for (int it = 0; it < myN; ++it) {
                const int j0 = jt << 6;
                const int jn = (it + 1 < myN) ? (jt + 4) : jt;

                // V loads for current tile (consumed after softmax)
                short8 vf0[4], vf1[4];
#pragma unroll
                for (int di = 0; di < 4; ++di) {
                    const unsigned short* Vrow = &VT[jt * 4096 + (di * 16 + lane15) * 64 + quad * 8];
                    vf0[di] = *(const short8*)Vrow;
                    vf1[di] = *(const short8*)(Vrow + 32);
                }
                // K prefetch for next tile
                short8 kn0[4], kn1[4];
#pragma unroll
                for (int ni = 0; ni < 4; ++ni) {
                    const unsigned short* Krow = &K[(jn * 64 + ni * 16 + lane15) * 64 + quad * 8];
                    kn0[ni] = *(const short8*)Krow;
                    kn1[ni] = *(const short8*)(Krow + 32);
                }

                // ---- S^T = K Q^T (already scaled so p = 2^s)
                f32x4 sv[4];
#pragma unroll
                for (int ni = 0; ni < 4; ++ni) {
                    f32x4 t = (f32x4){0.f, 0.f, 0.f, 0.f};
                    t = __builtin_amdgcn_mfma_f32_16x16x32_bf16(kc0[ni], qf0, t, 0, 0, 0);
                    t = __builtin_amdgcn_mfma_f32_16x16x32_bf16(kc1[ni], qf1, t, 0, 0, 0);
                    sv[ni] = t;
                }

                // only the LAST tile of a q-tile's range can be masked
                if (j0 + 63 > i0 + SRCL_) {
#pragma unroll
                    for (int ni = 0; ni < 4; ++ni)
#pragma unroll
                        for (int r = 0; r < 4; ++r) {
                            const int key = j0 + ni * 16 + quad * 4 + r;
                            if (key > limit) sv[ni][r] = -INFINITY;
                        }
                }

                // p = exp2(s); accumulate l; pack bf16 (round-half-up + v_perm)
                float lacc = 0.f;
#pragma unroll
                for (int ni = 0; ni < 4; ++ni) {
                    const float p0 = EXP2F(sv[ni][0]);
                    const float p1 = EXP2F(sv[ni][1]);
                    const float p2 = EXP2F(sv[ni][2]);
                    const float p3 = EXP2F(sv[ni][3]);
                    lacc += (p0 + p1) + (p2 + p3);
                    const unsigned u0 = __float_as_uint(p0) + 0x8000u;
                    const unsigned u1 = __float_as_uint(p1) + 0x8000u;
                    const unsigned u2 = __float_as_uint(p2) + 0x8000u;
                    const unsigned u3 = __float_as_uint(p3) + 0x8000u;
                    uint2 w;
                    w.x = __builtin_amdgcn_perm(u1, u0, 0x07060302);
                    w.y = __builtin_amdgcn_perm(u3, u2, 0x07060302);
                    *(uint2*)&myPs[lane15 * 88 + ni * 16 + quad * 4] = w;
                }
                l_p += lacc;

                // same-wave DS in-order; compiler inserts lgkmcnt before use
                const short8 pf0 = *(const short8*)&myPs[lane15 * 88 + quad * 8];
                const short8 pf1 = *(const short8*)&myPs[lane15 * 88 + 32 + quad * 8];

#pragma unroll
                for (int di = 0; di < 4; ++di) {
                    o_acc[di] = __builtin_amdgcn_mfma_f32_16x16x32_bf16(vf0[di], pf0, o_acc[di], 0, 0, 0);
                    o_acc[di] = __builtin_amdgcn_mfma_f32_16x16x32_bf16(vf1[di], pf1, o_acc[di], 0, 0, 0);
                }

#pragma unroll
                for (int ni = 0; ni < 4; ++ni) { kc0[ni] = kn0[ni]; kc1[ni] = kn1[ni]; }
                jt += 4;
            }
        }

        // per-lane partial denom -> per-query total (across quads)
        float l0s = l_p + __shfl_xor(l_p, 16);
        const float l_tot = l0s + __shfl_xor(l0s, 32);

        // merge slices: plain sums (no max rebasing needed)
        if (s > 0) {
#pragma unroll
            for (int di = 0; di < 4; ++di)
#pragma unroll
                for (int r = 0; r < 4; ++r)
                    Ob[s - 1][(di * 16 + quad * 4 + r) * 17 + lane15] = o_acc[di][r];
            if (lane < 16) Lb[s - 1][lane] = l_tot;
        }
        __syncthreads();
        if (s == 0) {
            float lsum = l_tot + Lb[0][lane15] + Lb[1][lane15] + Lb[2][lane15];
            const float inv = 1.0f / lsum;
            float* orow = out + ((size_t)(b * T_ + i0 + lane15)) * C_ + h * 64 + quad * 4;
#pragma unroll
            for (int di = 0; di < 4; ++di) {
                float4 v;
#pragma unroll
                for (int r = 0; r < 4; ++r) {
                    const int ri = (di * 16 + quad * 4 + r) * 17 + lane15;
                    ((float*)&v)[r] = (o_acc[di][r] + Ob[0][ri] + Ob[1][ri] + Ob[2][ri]) * inv;
                }
                *(float4*)(orow + di * 16) = v;
            }
        }
        __syncthreads();   // Ob/Lb reuse for next q-tile
    }
}

// ---------------------------------------------------------------------------
// Launch
// ---------------------------------------------------------------------------
extern "C" void kernel_launch(void* const* d_in, const int* in_sizes, int n_in,
                              void* d_out, int out_size, void* d_ws, size_t ws_size,
                              hipStream_t stream) {
    const float* x  = (const float*)d_in[0];
    const float* Wq = (const float*)d_in[1];
    const float* bq = (const float*)d_in[2];
    const float* Wk = (const float*)d_in[3];
    const float* bk = (const float*)d_in[4];
    const float* Wv = (const float*)d_in[5];
    const float* bv = (const float*)d_in[6];
    float* out = (float*)d_out;

    unsigned short* xb  = (unsigned short*)d_ws;            // 4096*1024
    unsigned short* wb  = xb  + (size_t)B_ * T_ * C_;       // 3*1024*1024
    unsigned short* qb  = wb  + (size_t)3 * C_ * C_;        // B*H*T*D
    unsigned short* kb  = qb  + (size_t)B_ * H_ * T_ * D_;
    unsigned short* vtb = kb  + (size_t)B_ * H_ * T_ * D_;  // tiled V^T

    convert_all<<<7168, 256, 0, stream>>>(x, Wq, Wk, Wv, xb, wb);
    gemm_qkv<<<768, 256, 0, stream>>>(xb, wb, bq, bk, bv, qb, kb, vtb);
    attn<<<1024, 256, 0, stream>>>(qb, kb, vtb, out);
}